// Round 4
// baseline (1150.698 us; speedup 1.0000x reference)
//
#include <hip/hip_runtime.h>
#include <hip/hip_cooperative_groups.h>
#include <math.h>

namespace cg = cooperative_groups;

// WaveNet forward, round 6 (2nd resubmit after broker timeouts): persistent
// cooperative kernel.
// - One block per (n, tile): 1024 blocks = 4/CU resident. All 30 layers run
//   inside one kernel with cg::grid().sync() between layers (needed for the
//   cross-block dilated tap0 read of h). Skip accumulator lives in registers
//   as packed f16 frags sk16[4][4] (32 VGPRs), re-rounded to f16 per layer
//   exactly like the old chunk RMW -> bit-identical numerics. Head is fused
//   (its input IS sk16). Deletes: chunk RMW (67 MB/layer), head chunk read,
//   29 launch gaps, last layer's res GEMM + h store.
// - Conv GEMM split into two mt-pair passes (acc 32 regs not 64), GLU staged
//   in 16 regs, so peak VGPR stays under the 128 needed for 4 waves/SIMD.
// - Safety: host checks hipOccupancyMaxActiveBlocksPerMultiprocessor >= 4
//   before cooperative launch; otherwise falls back to the round-5 path
//   (layer_kernel x30 + head_kernel), which is kept verbatim.
//
// MFMA 16x16x32_f16: A lane: A[m=lane&15][k=(lane>>4)*8+j]; D lane:
// D[row=(lane>>4)*4+reg][col=lane&15]. Conv A-rows interleaved (a0,b0,a1,b1..)
// so GLU happens in registers. Conv K order: k = tap*128 + c.

#define NB 4
#define WLEN 16384
#define C 128
#define S 256
#define NLAYERS 30
#define TT 64
#define NTB (WLEN / TT)   // 256 tiles per sample
#define XROW 264          // head X row stride (f16): 256 + 8 pad
#define GROW 136          // layer tile row stride (f16): 128 + 8 pad

typedef _Float16 half8 __attribute__((ext_vector_type(8)));
typedef _Float16 half4 __attribute__((ext_vector_type(4)));
typedef float floatx4 __attribute__((ext_vector_type(4)));

__device__ __forceinline__ float sigmoidf_(float v) {
    return 1.0f / (1.0f + __expf(-v));
}

// ---------------- weight packing ----------------
// cw : conv, per layer M=256 rows interleaved (m'=2r+s: s=0 a-row r, s=1 b-row r+128),
//      K=256 with k = tap*128 + c. Frag-linear [mt][ks][lane][8].
// rsw: res  M=128 K=128; skw: skip M=256 K=128; aw/bw: 256x256.
// cbp: conv bias interleaved; ssum: sum over layers of skip_b.
__global__ void prep_kernel(const float* __restrict__ conv_w,
                            const float* __restrict__ res_w,
                            const float* __restrict__ skip_w,
                            const float* __restrict__ a_w,
                            const float* __restrict__ b_w,
                            const float* __restrict__ conv_b,
                            const float* __restrict__ skip_b,
                            _Float16* __restrict__ cw,
                            _Float16* __restrict__ rsw,
                            _Float16* __restrict__ skw,
                            _Float16* __restrict__ aw,
                            _Float16* __restrict__ bw,
                            float* __restrict__ cbp,
                            float* __restrict__ ssum) {
    const int ncw = NLAYERS * 256 * 256;
    const int nrs = NLAYERS * 128 * 128;
    const int nsk = NLAYERS * 256 * 128;
    const int nab = 256 * 256;
    const int ncb = NLAYERS * 256;
    const int total = ncw + nrs + nsk + nab + nab + ncb + 256;
    for (int idx = blockIdx.x * blockDim.x + threadIdx.x; idx < total;
         idx += gridDim.x * blockDim.x) {
        int i = idx;
        if (i < ncw) {
            int j = i & 7, lane = (i >> 3) & 63, rest = i >> 9;
            int ks = rest & 7; rest >>= 3;
            int mt = rest & 15; int l = rest >> 4;
            int mp = mt * 16 + (lane & 15);
            int orow = (mp >> 1) + (mp & 1) * 128;
            int k = ks * 32 + (lane >> 4) * 8 + j;
            int tap = k >> 7, c = k & 127;
            cw[i] = (_Float16)conv_w[(((size_t)l * 256 + orow) * 128 + c) * 2 + tap];
        } else if (i < ncw + nrs) {
            i -= ncw;
            int j = i & 7, lane = (i >> 3) & 63, rest = i >> 9;
            int ks = rest & 3; rest >>= 2;
            int mt = rest & 7; int l = rest >> 3;
            int m = mt * 16 + (lane & 15);
            int k = ks * 32 + (lane >> 4) * 8 + j;
            rsw[i] = (_Float16)res_w[((size_t)l * 128 + m) * 128 + k];
        } else if (i < ncw + nrs + nsk) {
            i -= ncw + nrs;
            int j = i & 7, lane = (i >> 3) & 63, rest = i >> 9;
            int ks = rest & 3; rest >>= 2;
            int mt = rest & 15; int l = rest >> 4;
            int m = mt * 16 + (lane & 15);
            int k = ks * 32 + (lane >> 4) * 8 + j;
            skw[i] = (_Float16)skip_w[((size_t)l * 256 + m) * 128 + k];
        } else if (i < ncw + nrs + nsk + nab) {
            i -= ncw + nrs + nsk;
            int j = i & 7, lane = (i >> 3) & 63, rest = i >> 9;
            int ks = rest & 7; int mt = rest >> 3;
            aw[i] = (_Float16)a_w[(mt * 16 + (lane & 15)) * 256 + ks * 32 + (lane >> 4) * 8 + j];
        } else if (i < ncw + nrs + nsk + 2 * nab) {
            i -= ncw + nrs + nsk + nab;
            int j = i & 7, lane = (i >> 3) & 63, rest = i >> 9;
            int ks = rest & 7; int mt = rest >> 3;
            bw[i] = (_Float16)b_w[(mt * 16 + (lane & 15)) * 256 + ks * 32 + (lane >> 4) * 8 + j];
        } else if (i < ncw + nrs + nsk + 2 * nab + ncb) {
            i -= ncw + nrs + nsk + 2 * nab;
            int mp = i & 255; int l = i >> 8;
            cbp[i] = conv_b[l * 256 + (mp >> 1) + (mp & 1) * 128];
        } else {
            i -= ncw + nrs + nsk + 2 * nab + ncb;
            float s = 0.f;
            for (int l = 0; l < NLAYERS; ++l) s += skip_b[l * 256 + i];
            ssum[i] = s;
        }
    }
}

// ---------------- front: h0 (f16, [n][t][c]) ----------------
__global__ void front_kernel(const float* __restrict__ x,
                             const float* __restrict__ w_shift,
                             const float* __restrict__ b_shift,
                             _Float16* __restrict__ h) {
    const int n = blockIdx.y;
    const int t = blockIdx.x * 256 + threadIdx.x;
    float x1 = (t >= 1) ? x[n * WLEN + t - 1] : 0.0f;
    float x2 = (t >= 2) ? x[n * WLEN + t - 2] : 0.0f;
    _Float16* hq = h + ((size_t)n * WLEN + t) * 128;
    #pragma unroll
    for (int c0 = 0; c0 < 128; c0 += 8) {
        half8 v;
        #pragma unroll
        for (int j = 0; j < 8; ++j) {
            int c = c0 + j;
            v[j] = (_Float16)fmaf(w_shift[2 * c], x2,
                                  fmaf(w_shift[2 * c + 1], x1, b_shift[c]));
        }
        *(half8*)&hq[c0] = v;
    }
}

// ---------------- persistent cooperative kernel: 30 layers + head ----------------
__global__ __launch_bounds__(256, 4) void wavenet_coop(
    _Float16* __restrict__ hA, _Float16* __restrict__ hB,
    float* __restrict__ out,
    const _Float16* __restrict__ cw_all, const float* __restrict__ cbp_all,
    const _Float16* __restrict__ rsw_all, const float* __restrict__ rb_all,
    const _Float16* __restrict__ skw_all, const float* __restrict__ ssum,
    const _Float16* __restrict__ aw, const float* __restrict__ ab,
    const _Float16* __restrict__ bw, const float* __restrict__ bb) {
    __shared__ _Float16 SMEM[2 * TT * GROW];  // 34816 B -> 4 blocks/CU
    _Float16* X0 = SMEM;
    _Float16* X1 = SMEM + TT * GROW;
    _Float16* G  = X0;  // alias: tap0 dead after conv reads
    cg::grid_group gg = cg::this_grid();
    const int n = blockIdx.y, tb = blockIdx.x, t0 = tb * TT;
    const int tid = threadIdx.x;
    const int wave = __builtin_amdgcn_readfirstlane(tid >> 6);
    const int lane = tid & 63, q = lane >> 4, ml = lane & 15;

    half4 sk16[4][4];  // persistent packed skip accumulator (32 VGPRs)

    #pragma clang loop unroll(disable)
    for (int l = 0; l < NLAYERS; ++l) {
        const _Float16* hin = (l & 1) ? hB : hA;
        _Float16* hout      = (l & 1) ? hA : hB;
        const int d = 1 << (l % 10);
        const _Float16* cw  = cw_all  + (size_t)l * 65536;
        const float*    cb  = cbp_all + l * 256;
        const _Float16* rsw = rsw_all + (size_t)l * 16384;
        const float*    rb  = rb_all  + l * 128;
        const _Float16* skw = skw_all + (size_t)l * 32768;

        // ---- stage both taps: contiguous 16B row-segment copies
        const _Float16* hn = hin + (size_t)n * WLEN * 128;
        #pragma unroll
        for (int it = 0; it < 8; ++it) {
            int idx = it * 256 + tid;        // 0..2047
            int seg = idx & 15;              // 16B segment (8 f16)
            int rowc = (idx >> 4) & 63;      // dest row (t within tile)
            int tap = idx >> 10;             // 0: t-d, 1: t
            int src_t = t0 + rowc - (tap ? 0 : d);
            half8 v = (half8)(_Float16)0.0f;
            if (src_t >= 0)
                v = *(const half8*)&hn[(size_t)src_t * 128 + seg * 8];
            _Float16* Xb = tap ? X1 : X0;
            *(half8*)&Xb[rowc * GROW + seg * 8] = v;
        }
        __syncthreads();

        // ---- conv GEMM in two mt-pair passes (register diet); GLU staged in regs
        uint32_t glu[4][4];
        #pragma unroll
        for (int mp2 = 0; mp2 < 2; ++mp2) {
            floatx4 acc[2][4];
            #pragma unroll
            for (int i = 0; i < 2; ++i) {
                int mt = 2 * mp2 + i;
                #pragma unroll
                for (int r = 0; r < 4; ++r) {
                    float bias = cb[64 * wave + mt * 16 + q * 4 + r];
                    #pragma unroll
                    for (int nt = 0; nt < 4; ++nt) acc[i][nt][r] = bias;
                }
            }
            #pragma unroll
            for (int hp = 0; hp < 2; ++hp) {
                const _Float16* Xb = hp ? X1 : X0;
                for (int ks = 0; ks < 4; ++ks) {
                    half8 b[4];
                    #pragma unroll
                    for (int nt = 0; nt < 4; ++nt)
                        b[nt] = *(const half8*)&Xb[(nt * 16 + ml) * GROW + ks * 32 + q * 8];
                    #pragma unroll
                    for (int i = 0; i < 2; ++i) {
                        int mt = 2 * mp2 + i;
                        half8 a = *(const half8*)&cw[((((4 * wave + mt) * 8) + hp * 4 + ks) * 64 + lane) * 8];
                        #pragma unroll
                        for (int nt = 0; nt < 4; ++nt)
                            acc[i][nt] = __builtin_amdgcn_mfma_f32_16x16x32_f16(a, b[nt], acc[i][nt], 0, 0, 0);
                    }
                }
            }
            #pragma unroll
            for (int i = 0; i < 2; ++i)
                #pragma unroll
                for (int nt = 0; nt < 4; ++nt) {
                    float g0 = acc[i][nt][0] * sigmoidf_(acc[i][nt][1]);
                    float g1 = acc[i][nt][2] * sigmoidf_(acc[i][nt][3]);
                    _Float16 p[2] = {(_Float16)g0, (_Float16)g1};
                    glu[2 * mp2 + i][nt] = *(uint32_t*)p;
                }
        }
        __syncthreads();  // all conv reads of X0 done before G overwrites it
        #pragma unroll
        for (int mt = 0; mt < 4; ++mt)
            #pragma unroll
            for (int nt = 0; nt < 4; ++nt)
                *(uint32_t*)&G[(nt * 16 + ml) * GROW + 32 * wave + mt * 8 + 2 * q] = glu[mt][nt];
        __syncthreads();

        // ---- skip GEMM into persistent register accumulator
        {
            floatx4 sacc[4][4];
            if (l == 0) {
                #pragma unroll
                for (int mt = 0; mt < 4; ++mt)
                    #pragma unroll
                    for (int r = 0; r < 4; ++r) {
                        float bias = ssum[64 * wave + mt * 16 + q * 4 + r];
                        #pragma unroll
                        for (int nt = 0; nt < 4; ++nt) sacc[mt][nt][r] = bias;
                    }
            } else {
                #pragma unroll
                for (int mt = 0; mt < 4; ++mt)
                    #pragma unroll
                    for (int nt = 0; nt < 4; ++nt)
                        #pragma unroll
                        for (int r = 0; r < 4; ++r)
                            sacc[mt][nt][r] = (float)sk16[mt][nt][r];
            }
            #pragma unroll
            for (int ks = 0; ks < 4; ++ks) {
                half8 b[4];
                #pragma unroll
                for (int nt = 0; nt < 4; ++nt)
                    b[nt] = *(const half8*)&G[(nt * 16 + ml) * GROW + ks * 32 + q * 8];
                #pragma unroll
                for (int mt = 0; mt < 4; ++mt) {
                    half8 a = *(const half8*)&skw[((((4 * wave + mt) * 4) + ks) * 64 + lane) * 8];
                    #pragma unroll
                    for (int nt = 0; nt < 4; ++nt)
                        sacc[mt][nt] = __builtin_amdgcn_mfma_f32_16x16x32_f16(a, b[nt], sacc[mt][nt], 0, 0, 0);
                }
            }
            // pack back to f16 (same per-layer rounding as the old chunk RMW)
            #pragma unroll
            for (int mt = 0; mt < 4; ++mt)
                #pragma unroll
                for (int nt = 0; nt < 4; ++nt)
                    #pragma unroll
                    for (int r = 0; r < 4; ++r)
                        sk16[mt][nt][r] = (_Float16)sacc[mt][nt][r];
        }

        // ---- res GEMM + residual add + h store (dead on last layer)
        if (l != NLAYERS - 1) {
            floatx4 racc[2][4];
            #pragma unroll
            for (int mt = 0; mt < 2; ++mt)
                #pragma unroll
                for (int r = 0; r < 4; ++r) {
                    float bias = rb[32 * wave + mt * 16 + q * 4 + r];
                    #pragma unroll
                    for (int nt = 0; nt < 4; ++nt) racc[mt][nt][r] = bias;
                }
            #pragma unroll
            for (int ks = 0; ks < 4; ++ks) {
                half8 b[4];
                #pragma unroll
                for (int nt = 0; nt < 4; ++nt)
                    b[nt] = *(const half8*)&G[(nt * 16 + ml) * GROW + ks * 32 + q * 8];
                #pragma unroll
                for (int mt = 0; mt < 2; ++mt) {
                    half8 a = *(const half8*)&rsw[((((2 * wave + mt) * 4) + ks) * 64 + lane) * 8];
                    #pragma unroll
                    for (int nt = 0; nt < 4; ++nt)
                        racc[mt][nt] = __builtin_amdgcn_mfma_f32_16x16x32_f16(a, b[nt], racc[mt][nt], 0, 0, 0);
                }
            }
            _Float16* ho = hout + (size_t)n * WLEN * 128;
            #pragma unroll
            for (int mt = 0; mt < 2; ++mt)
                #pragma unroll
                for (int nt = 0; nt < 4; ++nt) {
                    int tt = nt * 16 + ml;
                    int c = 32 * wave + mt * 16 + q * 4;
                    half4 hv = *(const half4*)&X1[tt * GROW + c];  // tap1 = h_in(c,t)
                    half4 o;
                    #pragma unroll
                    for (int r = 0; r < 4; ++r)
                        o[r] = (_Float16)(racc[mt][nt][r] + (float)hv[r]);
                    *(half4*)&ho[(size_t)(t0 + tt) * 128 + c] = o;
                }
            gg.sync();  // h_out visible to all blocks before next layer's stage
        }
    }

    // ---------------- fused head: sk16 -> relu -> a_w -> relu -> b_w -> logits
    __syncthreads();  // skip-GEMM G reads done before X overwrite
    _Float16* X = SMEM;  // [64][XROW] = 33792 B <= 34816
    #pragma unroll
    for (int mt = 0; mt < 4; ++mt)
        #pragma unroll
        for (int nt = 0; nt < 4; ++nt) {
            half4 v = sk16[mt][nt];
            half4 z;
            #pragma unroll
            for (int r = 0; r < 4; ++r)
                z[r] = (_Float16)fmaxf((float)v[r], 0.0f);
            *(half4*)&X[(nt * 16 + ml) * XROW + 64 * wave + mt * 16 + q * 4] = z;
        }
    __syncthreads();

    floatx4 acc[4][4];
    // ---- z2 = relu(a_w @ z + a_b)
    #pragma unroll
    for (int mt = 0; mt < 4; ++mt)
        #pragma unroll
        for (int r = 0; r < 4; ++r) {
            float bias = ab[64 * wave + mt * 16 + q * 4 + r];
            #pragma unroll
            for (int nt = 0; nt < 4; ++nt) acc[mt][nt][r] = bias;
        }
    for (int ks = 0; ks < 8; ++ks) {
        half8 b[4];
        #pragma unroll
        for (int nt = 0; nt < 4; ++nt)
            b[nt] = *(const half8*)&X[(nt * 16 + ml) * XROW + ks * 32 + q * 8];
        #pragma unroll
        for (int mt = 0; mt < 4; ++mt) {
            half8 a = *(const half8*)&aw[((((4 * wave + mt) * 8) + ks) * 64 + lane) * 8];
            #pragma unroll
            for (int nt = 0; nt < 4; ++nt)
                acc[mt][nt] = __builtin_amdgcn_mfma_f32_16x16x32_f16(a, b[nt], acc[mt][nt], 0, 0, 0);
        }
    }
    __syncthreads();
    #pragma unroll
    for (int mt = 0; mt < 4; ++mt)
        #pragma unroll
        for (int nt = 0; nt < 4; ++nt) {
            half4 z;
            #pragma unroll
            for (int r = 0; r < 4; ++r)
                z[r] = (_Float16)fmaxf(acc[mt][nt][r], 0.0f);
            *(half4*)&X[(nt * 16 + ml) * XROW + 64 * wave + mt * 16 + q * 4] = z;
        }
    __syncthreads();

    // ---- logits = b_w @ z2 + b_b
    #pragma unroll
    for (int mt = 0; mt < 4; ++mt)
        #pragma unroll
        for (int r = 0; r < 4; ++r) {
            float bias = bb[64 * wave + mt * 16 + q * 4 + r];
            #pragma unroll
            for (int nt = 0; nt < 4; ++nt) acc[mt][nt][r] = bias;
        }
    for (int ks = 0; ks < 8; ++ks) {
        half8 b[4];
        #pragma unroll
        for (int nt = 0; nt < 4; ++nt)
            b[nt] = *(const half8*)&X[(nt * 16 + ml) * XROW + ks * 32 + q * 8];
        #pragma unroll
        for (int mt = 0; mt < 4; ++mt) {
            half8 a = *(const half8*)&bw[((((4 * wave + mt) * 8) + ks) * 64 + lane) * 8];
            #pragma unroll
            for (int nt = 0; nt < 4; ++nt)
                acc[mt][nt] = __builtin_amdgcn_mfma_f32_16x16x32_f16(a, b[nt], acc[mt][nt], 0, 0, 0);
        }
    }
    float* on = out + (size_t)n * S * WLEN;
    #pragma unroll
    for (int mt = 0; mt < 4; ++mt)
        #pragma unroll
        for (int nt = 0; nt < 4; ++nt)
            #pragma unroll
            for (int r = 0; r < 4; ++r) {
                int o = 64 * wave + mt * 16 + q * 4 + r;
                int tt = t0 + nt * 16 + ml;
                on[(size_t)o * WLEN + tt] = acc[mt][nt][r];
            }
}

// ---------------- round-5 fallback kernels (verbatim) ----------------
template <bool FIRST>
__global__ __launch_bounds__(256, 4) void layer_kernel(
    const _Float16* __restrict__ h_in, _Float16* __restrict__ h_out,
    _Float16* __restrict__ chunk,
    const _Float16* __restrict__ cw, const float* __restrict__ cb,
    const _Float16* __restrict__ rsw, const float* __restrict__ rb,
    const _Float16* __restrict__ skw, const float* __restrict__ ssum, int d) {
    __shared__ _Float16 SMEM[2 * TT * GROW];  // 34816 B
    _Float16* X0 = SMEM;
    _Float16* X1 = SMEM + TT * GROW;
    _Float16* G  = X0;
    const int n = blockIdx.y, tb = blockIdx.x, t0 = tb * TT;
    const int tid = threadIdx.x;
    const int wave = __builtin_amdgcn_readfirstlane(tid >> 6);
    const int lane = tid & 63, q = lane >> 4, ml = lane & 15;

    const _Float16* hn = h_in + (size_t)n * WLEN * 128;
    #pragma unroll
    for (int it = 0; it < 8; ++it) {
        int idx = it * 256 + tid;
        int seg = idx & 15;
        int rowc = (idx >> 4) & 63;
        int tap = idx >> 10;
        int src_t = t0 + rowc - (tap ? 0 : d);
        half8 v = (half8)(_Float16)0.0f;
        if (src_t >= 0)
            v = *(const half8*)&hn[(size_t)src_t * 128 + seg * 8];
        _Float16* Xb = tap ? X1 : X0;
        *(half8*)&Xb[rowc * GROW + seg * 8] = v;
    }
    __syncthreads();

    floatx4 acc[4][4];
    #pragma unroll
    for (int mt = 0; mt < 4; ++mt)
        #pragma unroll
        for (int r = 0; r < 4; ++r) {
            float bias = cb[64 * wave + mt * 16 + q * 4 + r];
            #pragma unroll
            for (int nt = 0; nt < 4; ++nt) acc[mt][nt][r] = bias;
        }
    #pragma unroll
    for (int hp = 0; hp < 2; ++hp) {
        const _Float16* Xb = hp ? X1 : X0;
        for (int ks = 0; ks < 4; ++ks) {
            half8 b[4];
            #pragma unroll
            for (int nt = 0; nt < 4; ++nt)
                b[nt] = *(const half8*)&Xb[(nt * 16 + ml) * GROW + ks * 32 + q * 8];
            #pragma unroll
            for (int mt = 0; mt < 4; ++mt) {
                half8 a = *(const half8*)&cw[((((4 * wave + mt) * 8) + hp * 4 + ks) * 64 + lane) * 8];
                #pragma unroll
                for (int nt = 0; nt < 4; ++nt)
                    acc[mt][nt] = __builtin_amdgcn_mfma_f32_16x16x32_f16(a, b[nt], acc[mt][nt], 0, 0, 0);
            }
        }
    }
    __syncthreads();

    #pragma unroll
    for (int mt = 0; mt < 4; ++mt)
        #pragma unroll
        for (int nt = 0; nt < 4; ++nt) {
            float g0 = acc[mt][nt][0] * sigmoidf_(acc[mt][nt][1]);
            float g1 = acc[mt][nt][2] * sigmoidf_(acc[mt][nt][3]);
            _Float16 p[2] = {(_Float16)g0, (_Float16)g1};
            *(uint32_t*)&G[(nt * 16 + ml) * GROW + 32 * wave + mt * 8 + 2 * q] = *(uint32_t*)p;
        }
    __syncthreads();

    {
        floatx4 sacc[4][4];
        #pragma unroll
        for (int mt = 0; mt < 4; ++mt)
            #pragma unroll
            for (int r = 0; r < 4; ++r) {
                float bias = FIRST ? ssum[64 * wave + mt * 16 + q * 4 + r] : 0.0f;
                #pragma unroll
                for (int nt = 0; nt < 4; ++nt) sacc[mt][nt][r] = bias;
            }
        #pragma unroll
        for (int ks = 0; ks < 4; ++ks) {
            half8 b[4];
            #pragma unroll
            for (int nt = 0; nt < 4; ++nt)
                b[nt] = *(const half8*)&G[(nt * 16 + ml) * GROW + ks * 32 + q * 8];
            #pragma unroll
            for (int mt = 0; mt < 4; ++mt) {
                half8 a = *(const half8*)&skw[((((4 * wave + mt) * 4) + ks) * 64 + lane) * 8];
                #pragma unroll
                for (int nt = 0; nt < 4; ++nt)
                    sacc[mt][nt] = __builtin_amdgcn_mfma_f32_16x16x32_f16(a, b[nt], sacc[mt][nt], 0, 0, 0);
            }
        }
        _Float16* cp = chunk + ((size_t)n * NTB + tb) * 16384;
        #pragma unroll
        for (int mt = 0; mt < 4; ++mt)
            #pragma unroll
            for (int nt = 0; nt < 4; ++nt) {
                size_t o = (size_t)((((wave * 4 + mt) * 4) + nt) * 64 + lane) * 4;
                if (FIRST) {
                    half4 v;
                    #pragma unroll
                    for (int r = 0; r < 4; ++r) v[r] = (_Float16)sacc[mt][nt][r];
                    *(half4*)&cp[o] = v;
                } else {
                    half4 v = *(const half4*)&cp[o];
                    half4 w;
                    #pragma unroll
                    for (int r = 0; r < 4; ++r)
                        w[r] = (_Float16)(sacc[mt][nt][r] + (float)v[r]);
                    *(half4*)&cp[o] = w;
                }
            }
    }

    {
        floatx4 racc[2][4];
        #pragma unroll
        for (int mt = 0; mt < 2; ++mt)
            #pragma unroll
            for (int r = 0; r < 4; ++r) {
                float bias = rb[32 * wave + mt * 16 + q * 4 + r];
                #pragma unroll
                for (int nt = 0; nt < 4; ++nt) racc[mt][nt][r] = bias;
            }
        #pragma unroll
        for (int ks = 0; ks < 4; ++ks) {
            half8 b[4];
            #pragma unroll
            for (int nt = 0; nt < 4; ++nt)
                b[nt] = *(const half8*)&G[(nt * 16 + ml) * GROW + ks * 32 + q * 8];
            #pragma unroll
            for (int mt = 0; mt < 2; ++mt) {
                half8 a = *(const half8*)&rsw[((((2 * wave + mt) * 4) + ks) * 64 + lane) * 8];
                #pragma unroll
                for (int nt = 0; nt < 4; ++nt)
                    racc[mt][nt] = __builtin_amdgcn_mfma_f32_16x16x32_f16(a, b[nt], racc[mt][nt], 0, 0, 0);
            }
        }
        _Float16* ho = h_out + (size_t)n * WLEN * 128;
        #pragma unroll
        for (int mt = 0; mt < 2; ++mt)
            #pragma unroll
            for (int nt = 0; nt < 4; ++nt) {
                int tt = nt * 16 + ml;
                int c = 32 * wave + mt * 16 + q * 4;
                half4 hv = *(const half4*)&X1[tt * GROW + c];
                half4 o;
                #pragma unroll
                for (int r = 0; r < 4; ++r)
                    o[r] = (_Float16)(racc[mt][nt][r] + (float)hv[r]);
                *(half4*)&ho[(size_t)(t0 + tt) * 128 + c] = o;
            }
    }
}

__global__ __launch_bounds__(256, 4) void head_kernel(
    float* __restrict__ out, const _Float16* __restrict__ chunk,
    const _Float16* __restrict__ aw, const float* __restrict__ ab,
    const _Float16* __restrict__ bw, const float* __restrict__ bb) {
    __shared__ _Float16 X[TT * XROW];
    const int n = blockIdx.y, tb = blockIdx.x, t0 = tb * TT;
    const int tid = threadIdx.x;
    const int wave = __builtin_amdgcn_readfirstlane(tid >> 6);
    const int lane = tid & 63, q = lane >> 4, ml = lane & 15;

    {
        const _Float16* cp = chunk + ((size_t)n * NTB + tb) * 16384;
        #pragma unroll
        for (int mt = 0; mt < 4; ++mt)
            #pragma unroll
            for (int nt = 0; nt < 4; ++nt) {
                size_t o = (size_t)((((wave * 4 + mt) * 4) + nt) * 64 + lane) * 4;
                half4 v = *(const half4*)&cp[o];
                half4 z;
                #pragma unroll
                for (int r = 0; r < 4; ++r)
                    z[r] = (_Float16)fmaxf((float)v[r], 0.0f);
                *(half4*)&X[(nt * 16 + ml) * XROW + 64 * wave + mt * 16 + q * 4] = z;
            }
    }
    __syncthreads();

    floatx4 acc[4][4];
    #pragma unroll
    for (int mt = 0; mt < 4; ++mt)
        #pragma unroll
        for (int r = 0; r < 4; ++r) {
            float bias = ab[64 * wave + mt * 16 + q * 4 + r];
            #pragma unroll
            for (int nt = 0; nt < 4; ++nt) acc[mt][nt][r] = bias;
        }
    for (int ks = 0; ks < 8; ++ks) {
        half8 b[4];
        #pragma unroll
        for (int nt = 0; nt < 4; ++nt)
            b[nt] = *(const half8*)&X[(nt * 16 + ml) * XROW + ks * 32 + q * 8];
        #pragma unroll
        for (int mt = 0; mt < 4; ++mt) {
            half8 a = *(const half8*)&aw[((((4 * wave + mt) * 8) + ks) * 64 + lane) * 8];
            #pragma unroll
            for (int nt = 0; nt < 4; ++nt)
                acc[mt][nt] = __builtin_amdgcn_mfma_f32_16x16x32_f16(a, b[nt], acc[mt][nt], 0, 0, 0);
        }
    }
    __syncthreads();
    #pragma unroll
    for (int mt = 0; mt < 4; ++mt)
        #pragma unroll
        for (int nt = 0; nt < 4; ++nt) {
            half4 z;
            #pragma unroll
            for (int r = 0; r < 4; ++r)
                z[r] = (_Float16)fmaxf(acc[mt][nt][r], 0.0f);
            *(half4*)&X[(nt * 16 + ml) * XROW + 64 * wave + mt * 16 + q * 4] = z;
        }
    __syncthreads();

    #pragma unroll
    for (int mt = 0; mt < 4; ++mt)
        #pragma unroll
        for (int r = 0; r < 4; ++r) {
            float bias = bb[64 * wave + mt * 16 + q * 4 + r];
            #pragma unroll
            for (int nt = 0; nt < 4; ++nt) acc[mt][nt][r] = bias;
        }
    for (int ks = 0; ks < 8; ++ks) {
        half8 b[4];
        #pragma unroll
        for (int nt = 0; nt < 4; ++nt)
            b[nt] = *(const half8*)&X[(nt * 16 + ml) * XROW + ks * 32 + q * 8];
        #pragma unroll
        for (int mt = 0; mt < 4; ++mt) {
            half8 a = *(const half8*)&bw[((((4 * wave + mt) * 8) + ks) * 64 + lane) * 8];
            #pragma unroll
            for (int nt = 0; nt < 4; ++nt)
                acc[mt][nt] = __builtin_amdgcn_mfma_f32_16x16x32_f16(a, b[nt], acc[mt][nt], 0, 0, 0);
        }
    }
    float* on = out + (size_t)n * S * WLEN;
    #pragma unroll
    for (int mt = 0; mt < 4; ++mt)
        #pragma unroll
        for (int nt = 0; nt < 4; ++nt)
            #pragma unroll
            for (int r = 0; r < 4; ++r) {
                int o = 64 * wave + mt * 16 + q * 4 + r;
                int tt = t0 + nt * 16 + ml;
                on[(size_t)o * WLEN + tt] = acc[mt][nt][r];
            }
}

extern "C" void kernel_launch(void* const* d_in, const int* in_sizes, int n_in,
                              void* d_out, int out_size, void* d_ws, size_t ws_size,
                              hipStream_t stream) {
    (void)in_sizes; (void)n_in; (void)out_size; (void)ws_size;
    const float* x       = (const float*)d_in[0];
    const float* w_shift = (const float*)d_in[1];
    const float* b_shift = (const float*)d_in[2];
    const float* conv_w  = (const float*)d_in[3];
    const float* conv_b  = (const float*)d_in[4];
    const float* res_w   = (const float*)d_in[5];
    const float* res_b   = (const float*)d_in[6];
    const float* skip_w  = (const float*)d_in[7];
    const float* skip_b  = (const float*)d_in[8];
    const float* a_w     = (const float*)d_in[9];
    const float* a_b     = (const float*)d_in[10];
    const float* b_w     = (const float*)d_in[11];
    const float* b_b     = (const float*)d_in[12];
    float* out = (float*)d_out;

    char* ws = (char*)d_ws;
    size_t off = 0;
    _Float16* hA    = (_Float16*)(ws + off); off += (size_t)NB * WLEN * 128 * 2;
    _Float16* hB    = (_Float16*)(ws + off); off += (size_t)NB * WLEN * 128 * 2;
    _Float16* chunk = (_Float16*)(ws + off); off += (size_t)NB * NTB * 16384 * 2;
    _Float16* cw  = (_Float16*)(ws + off); off += (size_t)NLAYERS * 256 * 256 * 2;
    _Float16* rsw = (_Float16*)(ws + off); off += (size_t)NLAYERS * 128 * 128 * 2;
    _Float16* skw = (_Float16*)(ws + off); off += (size_t)NLAYERS * 256 * 128 * 2;
    _Float16* aw  = (_Float16*)(ws + off); off += 256 * 256 * 2;
    _Float16* bw  = (_Float16*)(ws + off); off += 256 * 256 * 2;
    float* cbp  = (float*)(ws + off); off += (size_t)NLAYERS * 256 * 4;
    float* ssum = (float*)(ws + off); off += 256 * 4;
    // total ~74.3 MB

    prep_kernel<<<512, 256, 0, stream>>>(conv_w, res_w, skip_w, a_w, b_w,
                                         conv_b, skip_b,
                                         cw, rsw, skw, aw, bw, cbp, ssum);
    front_kernel<<<dim3(WLEN / 256, NB), 256, 0, stream>>>(x, w_shift, b_shift, hA);

    const dim3 grid(NTB, NB);

    // cooperative path requires full 4-blocks/CU residency (1024 blocks)
    static int coop_blocks_per_cu = -1;
    if (coop_blocks_per_cu < 0) {
        int nb = 0;
        if (hipOccupancyMaxActiveBlocksPerMultiprocessor(&nb, wavenet_coop, 256, 0)
            != hipSuccess)
            nb = 0;
        coop_blocks_per_cu = nb;
    }

    bool launched = false;
    if (coop_blocks_per_cu >= 4) {
        void* args[] = {&hA, &hB, &out, &cw, &cbp, &rsw, (void*)&res_b,
                        &skw, &ssum, &aw, (void*)&a_b, &bw, (void*)&b_b};
        launched = hipLaunchCooperativeKernel((const void*)wavenet_coop, grid,
                                              dim3(256), args, 0, stream) == hipSuccess;
    }

    if (!launched) {
        // round-5 fallback: per-layer kernels + chunk RMW + separate head
        _Float16* hin = hA;
        _Float16* hout = hB;
        for (int l = 0; l < NLAYERS; ++l) {
            int dil = 1 << (l % 10);
            const _Float16* cwp = cw + (size_t)l * 65536;
            const _Float16* rsp = rsw + (size_t)l * 16384;
            const _Float16* skp = skw + (size_t)l * 32768;
            if (l == 0)
                layer_kernel<true><<<grid, 256, 0, stream>>>(
                    hin, hout, chunk, cwp, cbp + l * 256,
                    rsp, res_b + l * 128, skp, ssum, dil);
            else
                layer_kernel<false><<<grid, 256, 0, stream>>>(
                    hin, hout, chunk, cwp, cbp + l * 256,
                    rsp, res_b + l * 128, skp, ssum, dil);
            _Float16* tmp = hin; hin = hout; hout = tmp;
        }
        head_kernel<<<grid, 256, 0, stream>>>(out, chunk, aw, a_b, bw, b_b);
    }
}

// Round 6
// 1099.977 us; speedup vs baseline: 1.0461x; 1.0461x over previous
//
#include <hip/hip_runtime.h>
#include <math.h>

// WaveNet forward, round 7 (resubmit after broker timeout): 8-wave blocks for
// 100% occupancy.
// - Coop/grid.sync path DELETED: rocprof showed wavenet_coop at 5536 us/dispatch
//   (5x slower than the kernel-per-layer pipeline; grid.sync + cross-XCD
//   coherence destroyed L2 locality). Kernel boundaries are the cheap barrier.
// - layer/head now 512 threads (8 waves), same TT=64 tile, same LDS (34816 B):
//   4 blocks/CU x 8 waves = 32 waves/CU (100%), up from 16 (50%).
//   Per-wave M ownership halved (conv/skip 2 mtiles, res 1) -> acc regs
//   32/32/16, targeting the <=64 VGPR budget needed for 8 waves/SIMD.
//   __launch_bounds__(512, 8).
// - Weight traffic unchanged (1024 blocks, full-layer weights per block, L2-hot).
//
// MFMA 16x16x32_f16: A lane: A[m=lane&15][k=(lane>>4)*8+j]; D lane:
// D[row=(lane>>4)*4+reg][col=lane&15]. Conv A-rows interleaved (a0,b0,a1,b1..)
// so GLU happens in registers. Conv K order: k = tap*128 + c.

#define NB 4
#define WLEN 16384
#define C 128
#define S 256
#define NLAYERS 30
#define TT 64
#define NTB (WLEN / TT)   // 256 tiles per sample
#define XROW 264          // head X row stride (f16): 256 + 8 pad
#define GROW 136          // layer tile row stride (f16): 128 + 8 pad

typedef _Float16 half8 __attribute__((ext_vector_type(8)));
typedef _Float16 half4 __attribute__((ext_vector_type(4)));
typedef float floatx4 __attribute__((ext_vector_type(4)));

__device__ __forceinline__ float sigmoidf_(float v) {
    return 1.0f / (1.0f + __expf(-v));
}

// ---------------- weight packing (unchanged layouts) ----------------
// cw : conv, per layer M=256 rows interleaved (m'=2r+s: s=0 a-row r, s=1 b-row r+128),
//      K=256 with k = tap*128 + c. Frag-linear [mtile 0..15][ks 0..7][lane][8].
// rsw: res  M=128 K=128 [mtile 0..7][ks 0..3][lane][8];
// skw: skip M=256 K=128 [mtile 0..15][ks 0..3][lane][8]; aw/bw: 256x256.
// cbp: conv bias interleaved; ssum: sum over layers of skip_b.
__global__ void prep_kernel(const float* __restrict__ conv_w,
                            const float* __restrict__ res_w,
                            const float* __restrict__ skip_w,
                            const float* __restrict__ a_w,
                            const float* __restrict__ b_w,
                            const float* __restrict__ conv_b,
                            const float* __restrict__ skip_b,
                            _Float16* __restrict__ cw,
                            _Float16* __restrict__ rsw,
                            _Float16* __restrict__ skw,
                            _Float16* __restrict__ aw,
                            _Float16* __restrict__ bw,
                            float* __restrict__ cbp,
                            float* __restrict__ ssum) {
    const int ncw = NLAYERS * 256 * 256;
    const int nrs = NLAYERS * 128 * 128;
    const int nsk = NLAYERS * 256 * 128;
    const int nab = 256 * 256;
    const int ncb = NLAYERS * 256;
    const int total = ncw + nrs + nsk + nab + nab + ncb + 256;
    for (int idx = blockIdx.x * blockDim.x + threadIdx.x; idx < total;
         idx += gridDim.x * blockDim.x) {
        int i = idx;
        if (i < ncw) {
            int j = i & 7, lane = (i >> 3) & 63, rest = i >> 9;
            int ks = rest & 7; rest >>= 3;
            int mt = rest & 15; int l = rest >> 4;
            int mp = mt * 16 + (lane & 15);
            int orow = (mp >> 1) + (mp & 1) * 128;
            int k = ks * 32 + (lane >> 4) * 8 + j;
            int tap = k >> 7, c = k & 127;
            cw[i] = (_Float16)conv_w[(((size_t)l * 256 + orow) * 128 + c) * 2 + tap];
        } else if (i < ncw + nrs) {
            i -= ncw;
            int j = i & 7, lane = (i >> 3) & 63, rest = i >> 9;
            int ks = rest & 3; rest >>= 2;
            int mt = rest & 7; int l = rest >> 3;
            int m = mt * 16 + (lane & 15);
            int k = ks * 32 + (lane >> 4) * 8 + j;
            rsw[i] = (_Float16)res_w[((size_t)l * 128 + m) * 128 + k];
        } else if (i < ncw + nrs + nsk) {
            i -= ncw + nrs;
            int j = i & 7, lane = (i >> 3) & 63, rest = i >> 9;
            int ks = rest & 3; rest >>= 2;
            int mt = rest & 15; int l = rest >> 4;
            int m = mt * 16 + (lane & 15);
            int k = ks * 32 + (lane >> 4) * 8 + j;
            skw[i] = (_Float16)skip_w[((size_t)l * 256 + m) * 128 + k];
        } else if (i < ncw + nrs + nsk + nab) {
            i -= ncw + nrs + nsk;
            int j = i & 7, lane = (i >> 3) & 63, rest = i >> 9;
            int ks = rest & 7; int mt = rest >> 3;
            aw[i] = (_Float16)a_w[(mt * 16 + (lane & 15)) * 256 + ks * 32 + (lane >> 4) * 8 + j];
        } else if (i < ncw + nrs + nsk + 2 * nab) {
            i -= ncw + nrs + nsk + nab;
            int j = i & 7, lane = (i >> 3) & 63, rest = i >> 9;
            int ks = rest & 7; int mt = rest >> 3;
            bw[i] = (_Float16)b_w[(mt * 16 + (lane & 15)) * 256 + ks * 32 + (lane >> 4) * 8 + j];
        } else if (i < ncw + nrs + nsk + 2 * nab + ncb) {
            i -= ncw + nrs + nsk + 2 * nab;
            int mp = i & 255; int l = i >> 8;
            cbp[i] = conv_b[l * 256 + (mp >> 1) + (mp & 1) * 128];
        } else {
            i -= ncw + nrs + nsk + 2 * nab + ncb;
            float s = 0.f;
            for (int l = 0; l < NLAYERS; ++l) s += skip_b[l * 256 + i];
            ssum[i] = s;
        }
    }
}

// ---------------- front: h0 (f16, [n][t][c]) ----------------
__global__ void front_kernel(const float* __restrict__ x,
                             const float* __restrict__ w_shift,
                             const float* __restrict__ b_shift,
                             _Float16* __restrict__ h) {
    const int n = blockIdx.y;
    const int t = blockIdx.x * 256 + threadIdx.x;
    float x1 = (t >= 1) ? x[n * WLEN + t - 1] : 0.0f;
    float x2 = (t >= 2) ? x[n * WLEN + t - 2] : 0.0f;
    _Float16* hq = h + ((size_t)n * WLEN + t) * 128;
    #pragma unroll
    for (int c0 = 0; c0 < 128; c0 += 8) {
        half8 v;
        #pragma unroll
        for (int j = 0; j < 8; ++j) {
            int c = c0 + j;
            v[j] = (_Float16)fmaf(w_shift[2 * c], x2,
                                  fmaf(w_shift[2 * c + 1], x1, b_shift[c]));
        }
        *(half8*)&hq[c0] = v;
    }
}

// ---------------- one residual layer, 8 waves ----------------
// Wave w owns: conv mtiles {2w,2w+1} (rows 32w..32w+31 of interleaved M=256),
// skip mtiles {2w,2w+1}, res mtile {w} (rows 16w..16w+15).
template <bool FIRST>
__global__ __launch_bounds__(512, 8) void layer_kernel(
    const _Float16* __restrict__ h_in, _Float16* __restrict__ h_out,
    _Float16* __restrict__ chunk,
    const _Float16* __restrict__ cw, const float* __restrict__ cb,
    const _Float16* __restrict__ rsw, const float* __restrict__ rb,
    const _Float16* __restrict__ skw, const float* __restrict__ ssum, int d) {
    __shared__ _Float16 SMEM[2 * TT * GROW];  // 34816 B -> 4 blocks/CU, 32 waves
    _Float16* X0 = SMEM;
    _Float16* X1 = SMEM + TT * GROW;
    _Float16* G  = X0;  // alias: tap0 dead after conv reads
    const int n = blockIdx.y, tb = blockIdx.x, t0 = tb * TT;
    const int tid = threadIdx.x;
    const int wave = __builtin_amdgcn_readfirstlane(tid >> 6);  // 0..7
    const int lane = tid & 63, q = lane >> 4, ml = lane & 15;

    // ---- stage both taps: 2048 contiguous 16B segments over 512 threads
    const _Float16* hn = h_in + (size_t)n * WLEN * 128;
    #pragma unroll
    for (int it = 0; it < 4; ++it) {
        int idx = it * 512 + tid;        // 0..2047
        int seg = idx & 15;              // 16B segment (8 f16)
        int rowc = (idx >> 4) & 63;      // dest row (t within tile)
        int tap = idx >> 10;             // 0: t-d, 1: t
        int src_t = t0 + rowc - (tap ? 0 : d);
        half8 v = (half8)(_Float16)0.0f;
        if (src_t >= 0)
            v = *(const half8*)&hn[(size_t)src_t * 128 + seg * 8];
        _Float16* Xb = tap ? X1 : X0;
        *(half8*)&Xb[rowc * GROW + seg * 8] = v;
    }
    __syncthreads();

    // ---- conv GEMM: D[m'][t], K=256 (k = tap*128 + c); acc 2x4
    floatx4 acc[2][4];
    #pragma unroll
    for (int mt = 0; mt < 2; ++mt)
        #pragma unroll
        for (int r = 0; r < 4; ++r) {
            float bias = cb[32 * wave + mt * 16 + q * 4 + r];
            #pragma unroll
            for (int nt = 0; nt < 4; ++nt) acc[mt][nt][r] = bias;
        }
    #pragma unroll
    for (int hp = 0; hp < 2; ++hp) {
        const _Float16* Xb = hp ? X1 : X0;
        for (int ks = 0; ks < 4; ++ks) {
            half8 a[2];
            #pragma unroll
            for (int mt = 0; mt < 2; ++mt)
                a[mt] = *(const half8*)&cw[((((2 * wave + mt) * 8) + hp * 4 + ks) * 64 + lane) * 8];
            #pragma unroll
            for (int nt = 0; nt < 4; ++nt) {
                half8 b = *(const half8*)&Xb[(nt * 16 + ml) * GROW + ks * 32 + q * 8];
                #pragma unroll
                for (int mt = 0; mt < 2; ++mt)
                    acc[mt][nt] = __builtin_amdgcn_mfma_f32_16x16x32_f16(a[mt], b, acc[mt][nt], 0, 0, 0);
            }
        }
    }
    __syncthreads();  // all conv reads of X0 done before G overwrites it

    // ---- GLU in registers -> G[t][r] (aliases X0; X1 keeps residual taps)
    #pragma unroll
    for (int mt = 0; mt < 2; ++mt)
        #pragma unroll
        for (int nt = 0; nt < 4; ++nt) {
            float g0 = acc[mt][nt][0] * sigmoidf_(acc[mt][nt][1]);
            float g1 = acc[mt][nt][2] * sigmoidf_(acc[mt][nt][3]);
            _Float16 p[2] = {(_Float16)g0, (_Float16)g1};
            *(uint32_t*)&G[(nt * 16 + ml) * GROW + 16 * wave + mt * 8 + 2 * q] = *(uint32_t*)p;
        }
    __syncthreads();

    // ---- skip GEMM (M=256, wave owns mtiles 2w,2w+1) + f16 frag-linear RMW
    {
        floatx4 sacc[2][4];
        #pragma unroll
        for (int mt = 0; mt < 2; ++mt)
            #pragma unroll
            for (int r = 0; r < 4; ++r) {
                float bias = FIRST ? ssum[32 * wave + mt * 16 + q * 4 + r] : 0.0f;
                #pragma unroll
                for (int nt = 0; nt < 4; ++nt) sacc[mt][nt][r] = bias;
            }
        #pragma unroll
        for (int ks = 0; ks < 4; ++ks) {
            half8 a[2];
            #pragma unroll
            for (int mt = 0; mt < 2; ++mt)
                a[mt] = *(const half8*)&skw[((((2 * wave + mt) * 4) + ks) * 64 + lane) * 8];
            #pragma unroll
            for (int nt = 0; nt < 4; ++nt) {
                half8 b = *(const half8*)&G[(nt * 16 + ml) * GROW + ks * 32 + q * 8];
                #pragma unroll
                for (int mt = 0; mt < 2; ++mt)
                    sacc[mt][nt] = __builtin_amdgcn_mfma_f32_16x16x32_f16(a[mt], b, sacc[mt][nt], 0, 0, 0);
            }
        }
        _Float16* cp = chunk + ((size_t)n * NTB + tb) * 16384;
        #pragma unroll
        for (int mt = 0; mt < 2; ++mt)
            #pragma unroll
            for (int nt = 0; nt < 4; ++nt) {
                size_t o = (size_t)((((wave * 2 + mt) * 4) + nt) * 64 + lane) * 4;
                if (FIRST) {
                    half4 v;
                    #pragma unroll
                    for (int r = 0; r < 4; ++r) v[r] = (_Float16)sacc[mt][nt][r];
                    *(half4*)&cp[o] = v;
                } else {
                    half4 v = *(const half4*)&cp[o];
                    half4 w;
                    #pragma unroll
                    for (int r = 0; r < 4; ++r)
                        w[r] = (_Float16)(sacc[mt][nt][r] + (float)v[r]);
                    *(half4*)&cp[o] = w;
                }
            }
    }

    // ---- res GEMM (M=128, wave owns mtile w) + residual add
    {
        floatx4 racc[4];
        #pragma unroll
        for (int r = 0; r < 4; ++r) {
            float bias = rb[16 * wave + q * 4 + r];
            #pragma unroll
            for (int nt = 0; nt < 4; ++nt) racc[nt][r] = bias;
        }
        #pragma unroll
        for (int ks = 0; ks < 4; ++ks) {
            half8 a = *(const half8*)&rsw[(((wave * 4) + ks) * 64 + lane) * 8];
            #pragma unroll
            for (int nt = 0; nt < 4; ++nt) {
                half8 b = *(const half8*)&G[(nt * 16 + ml) * GROW + ks * 32 + q * 8];
                racc[nt] = __builtin_amdgcn_mfma_f32_16x16x32_f16(a, b, racc[nt], 0, 0, 0);
            }
        }
        _Float16* ho = h_out + (size_t)n * WLEN * 128;
        #pragma unroll
        for (int nt = 0; nt < 4; ++nt) {
            int tt = nt * 16 + ml;
            int c = 16 * wave + q * 4;
            half4 hv = *(const half4*)&X1[tt * GROW + c];  // tap1 = h_in(c,t)
            half4 o;
            #pragma unroll
            for (int r = 0; r < 4; ++r)
                o[r] = (_Float16)(racc[nt][r] + (float)hv[r]);
            *(half4*)&ho[(size_t)(t0 + tt) * 128 + c] = o;
        }
    }
}

// ---------------- head: chunk -> relu -> a_w -> relu -> b_w -> logits, 8 waves ----------------
__global__ __launch_bounds__(512, 8) void head_kernel(
    float* __restrict__ out, const _Float16* __restrict__ chunk,
    const _Float16* __restrict__ aw, const float* __restrict__ ab,
    const _Float16* __restrict__ bw, const float* __restrict__ bb) {
    __shared__ _Float16 X[TT * XROW];  // 33792 B -> 4 blocks/CU, 32 waves
    const int n = blockIdx.y, tb = blockIdx.x, t0 = tb * TT;
    const int tid = threadIdx.x;
    const int wave = __builtin_amdgcn_readfirstlane(tid >> 6);  // 0..7
    const int lane = tid & 63, q = lane >> 4, ml = lane & 15;

    // ---- z = relu(skips) from frag-linear chunk -> X[t][s]
    {
        const _Float16* cp = chunk + ((size_t)n * NTB + tb) * 16384;
        #pragma unroll
        for (int mt = 0; mt < 2; ++mt)
            #pragma unroll
            for (int nt = 0; nt < 4; ++nt) {
                size_t o = (size_t)((((wave * 2 + mt) * 4) + nt) * 64 + lane) * 4;
                half4 v = *(const half4*)&cp[o];
                half4 z;
                #pragma unroll
                for (int r = 0; r < 4; ++r)
                    z[r] = (_Float16)fmaxf((float)v[r], 0.0f);
                *(half4*)&X[(nt * 16 + ml) * XROW + 32 * wave + mt * 16 + q * 4] = z;
            }
    }
    __syncthreads();

    floatx4 acc[2][4];
    // ---- z2 = relu(a_w @ z + a_b)
    #pragma unroll
    for (int mt = 0; mt < 2; ++mt)
        #pragma unroll
        for (int r = 0; r < 4; ++r) {
            float bias = ab[32 * wave + mt * 16 + q * 4 + r];
            #pragma unroll
            for (int nt = 0; nt < 4; ++nt) acc[mt][nt][r] = bias;
        }
    for (int ks = 0; ks < 8; ++ks) {
        half8 a[2];
        #pragma unroll
        for (int mt = 0; mt < 2; ++mt)
            a[mt] = *(const half8*)&aw[((((2 * wave + mt) * 8) + ks) * 64 + lane) * 8];
        #pragma unroll
        for (int nt = 0; nt < 4; ++nt) {
            half8 b = *(const half8*)&X[(nt * 16 + ml) * XROW + ks * 32 + q * 8];
            #pragma unroll
            for (int mt = 0; mt < 2; ++mt)
                acc[mt][nt] = __builtin_amdgcn_mfma_f32_16x16x32_f16(a[mt], b, acc[mt][nt], 0, 0, 0);
        }
    }
    __syncthreads();
    #pragma unroll
    for (int mt = 0; mt < 2; ++mt)
        #pragma unroll
        for (int nt = 0; nt < 4; ++nt) {
            half4 z;
            #pragma unroll
            for (int r = 0; r < 4; ++r)
                z[r] = (_Float16)fmaxf(acc[mt][nt][r], 0.0f);
            *(half4*)&X[(nt * 16 + ml) * XROW + 32 * wave + mt * 16 + q * 4] = z;
        }
    __syncthreads();

    // ---- logits = b_w @ z2 + b_b
    #pragma unroll
    for (int mt = 0; mt < 2; ++mt)
        #pragma unroll
        for (int r = 0; r < 4; ++r) {
            float bias = bb[32 * wave + mt * 16 + q * 4 + r];
            #pragma unroll
            for (int nt = 0; nt < 4; ++nt) acc[mt][nt][r] = bias;
        }
    for (int ks = 0; ks < 8; ++ks) {
        half8 a[2];
        #pragma unroll
        for (int mt = 0; mt < 2; ++mt)
            a[mt] = *(const half8*)&bw[((((2 * wave + mt) * 8) + ks) * 64 + lane) * 8];
        #pragma unroll
        for (int nt = 0; nt < 4; ++nt) {
            half8 b = *(const half8*)&X[(nt * 16 + ml) * XROW + ks * 32 + q * 8];
            #pragma unroll
            for (int mt = 0; mt < 2; ++mt)
                acc[mt][nt] = __builtin_amdgcn_mfma_f32_16x16x32_f16(a[mt], b, acc[mt][nt], 0, 0, 0);
        }
    }
    float* on = out + (size_t)n * S * WLEN;
    #pragma unroll
    for (int mt = 0; mt < 2; ++mt)
        #pragma unroll
        for (int nt = 0; nt < 4; ++nt)
            #pragma unroll
            for (int r = 0; r < 4; ++r) {
                int o = 32 * wave + mt * 16 + q * 4 + r;
                int tt = t0 + nt * 16 + ml;
                on[(size_t)o * WLEN + tt] = acc[mt][nt][r];
            }
}

extern "C" void kernel_launch(void* const* d_in, const int* in_sizes, int n_in,
                              void* d_out, int out_size, void* d_ws, size_t ws_size,
                              hipStream_t stream) {
    (void)in_sizes; (void)n_in; (void)out_size; (void)ws_size;
    const float* x       = (const float*)d_in[0];
    const float* w_shift = (const float*)d_in[1];
    const float* b_shift = (const float*)d_in[2];
    const float* conv_w  = (const float*)d_in[3];
    const float* conv_b  = (const float*)d_in[4];
    const float* res_w   = (const float*)d_in[5];
    const float* res_b   = (const float*)d_in[6];
    const float* skip_w  = (const float*)d_in[7];
    const float* skip_b  = (const float*)d_in[8];
    const float* a_w     = (const float*)d_in[9];
    const float* a_b     = (const float*)d_in[10];
    const float* b_w     = (const float*)d_in[11];
    const float* b_b     = (const float*)d_in[12];
    float* out = (float*)d_out;

    char* ws = (char*)d_ws;
    size_t off = 0;
    _Float16* hA    = (_Float16*)(ws + off); off += (size_t)NB * WLEN * 128 * 2;
    _Float16* hB    = (_Float16*)(ws + off); off += (size_t)NB * WLEN * 128 * 2;
    _Float16* chunk = (_Float16*)(ws + off); off += (size_t)NB * NTB * 16384 * 2;
    _Float16* cw  = (_Float16*)(ws + off); off += (size_t)NLAYERS * 256 * 256 * 2;
    _Float16* rsw = (_Float16*)(ws + off); off += (size_t)NLAYERS * 128 * 128 * 2;
    _Float16* skw = (_Float16*)(ws + off); off += (size_t)NLAYERS * 256 * 128 * 2;
    _Float16* aw  = (_Float16*)(ws + off); off += 256 * 256 * 2;
    _Float16* bw  = (_Float16*)(ws + off); off += 256 * 256 * 2;
    float* cbp  = (float*)(ws + off); off += (size_t)NLAYERS * 256 * 4;
    float* ssum = (float*)(ws + off); off += 256 * 4;
    // total ~74.3 MB

    prep_kernel<<<512, 256, 0, stream>>>(conv_w, res_w, skip_w, a_w, b_w,
                                         conv_b, skip_b,
                                         cw, rsw, skw, aw, bw, cbp, ssum);
    front_kernel<<<dim3(WLEN / 256, NB), 256, 0, stream>>>(x, w_shift, b_shift, hA);

    const dim3 grid(NTB, NB);
    _Float16* hin = hA;
    _Float16* hout = hB;
    for (int l = 0; l < NLAYERS; ++l) {
        int dil = 1 << (l % 10);
        const _Float16* cwp = cw + (size_t)l * 65536;
        const _Float16* rsp = rsw + (size_t)l * 16384;
        const _Float16* skp = skw + (size_t)l * 32768;
        if (l == 0)
            layer_kernel<true><<<grid, 512, 0, stream>>>(
                hin, hout, chunk, cwp, cbp + l * 256,
                rsp, res_b + l * 128, skp, ssum, dil);
        else
            layer_kernel<false><<<grid, 512, 0, stream>>>(
                hin, hout, chunk, cwp, cbp + l * 256,
                rsp, res_b + l * 128, skp, ssum, dil);
        _Float16* tmp = hin; hin = hout; hout = tmp;
    }

    head_kernel<<<grid, 512, 0, stream>>>(out, chunk, aw, a_b, bw, b_b);
}

// Round 8
// 1099.107 us; speedup vs baseline: 1.0469x; 1.0008x over previous
//
#include <hip/hip_runtime.h>
#include <math.h>

// WaveNet forward, round 8 (resubmit after broker timeout): dilation-aware
// stack fusion.
// - Layers with d=1,2,4,8,16,32 (halo sum 63 < 64) fused into ONE kernel per
//   stack (stack_kernel): block stages a 128-row h window (64 halo + 64 valid)
//   and runs all 6 layers in LDS with in-place h updates + halo recompute
//   (recomputed halo rows are bit-identical to the neighbor tile's valid rows,
//   so h stays consistent). Eliminates 5 h HBM round-trips per stack (~1 GB
//   total) and 15 of 30 launches. Skip accum for the 6 layers lives in f32
//   registers; one chunk store/load per stack.
// - Valid-region handling: compute ALL 8 row-tiles uniformly every layer
//   (compile-time indexing, no scratch); clamp tap0 row to >=0. Garbage rows
//   stay strictly below each layer's valid start (v_j = 2^(j+1)-1 <= 63) and
//   are never read by valid outputs.
// - LDS 2x128x136 f16 = 69632 B -> 2 blocks/CU; LDS-capped occupancy means
//   VGPR budget 128 is free -> __launch_bounds__(512, 4).
// - d=64..512 layers (12) keep the round-7 8-wave single-layer kernel.
// - Coop/grid.sync path stays deleted (measured 5x regression, round 4).
//
// MFMA 16x16x32_f16: A lane: A[m=lane&15][k=(lane>>4)*8+j]; D lane:
// D[row=(lane>>4)*4+reg][col=lane&15]. Conv A-rows interleaved (a0,b0,a1,b1..)
// so GLU happens in registers. Conv K order: k = tap*128 + c.

#define NB 4
#define WLEN 16384
#define C 128
#define S 256
#define NLAYERS 30
#define TT 64
#define NTB (WLEN / TT)   // 256 tiles per sample
#define XROW 264          // head X row stride (f16): 256 + 8 pad
#define GROW 136          // tile row stride (f16): 128 + 8 pad
#define HW 128            // fused-kernel window rows

typedef _Float16 half8 __attribute__((ext_vector_type(8)));
typedef _Float16 half4 __attribute__((ext_vector_type(4)));
typedef float floatx4 __attribute__((ext_vector_type(4)));

__device__ __forceinline__ float sigmoidf_(float v) {
    return 1.0f / (1.0f + __expf(-v));
}

// ---------------- weight packing (unchanged layouts) ----------------
__global__ void prep_kernel(const float* __restrict__ conv_w,
                            const float* __restrict__ res_w,
                            const float* __restrict__ skip_w,
                            const float* __restrict__ a_w,
                            const float* __restrict__ b_w,
                            const float* __restrict__ conv_b,
                            const float* __restrict__ skip_b,
                            _Float16* __restrict__ cw,
                            _Float16* __restrict__ rsw,
                            _Float16* __restrict__ skw,
                            _Float16* __restrict__ aw,
                            _Float16* __restrict__ bw,
                            float* __restrict__ cbp,
                            float* __restrict__ ssum) {
    const int ncw = NLAYERS * 256 * 256;
    const int nrs = NLAYERS * 128 * 128;
    const int nsk = NLAYERS * 256 * 128;
    const int nab = 256 * 256;
    const int ncb = NLAYERS * 256;
    const int total = ncw + nrs + nsk + nab + nab + ncb + 256;
    for (int idx = blockIdx.x * blockDim.x + threadIdx.x; idx < total;
         idx += gridDim.x * blockDim.x) {
        int i = idx;
        if (i < ncw) {
            int j = i & 7, lane = (i >> 3) & 63, rest = i >> 9;
            int ks = rest & 7; rest >>= 3;
            int mt = rest & 15; int l = rest >> 4;
            int mp = mt * 16 + (lane & 15);
            int orow = (mp >> 1) + (mp & 1) * 128;
            int k = ks * 32 + (lane >> 4) * 8 + j;
            int tap = k >> 7, c = k & 127;
            cw[i] = (_Float16)conv_w[(((size_t)l * 256 + orow) * 128 + c) * 2 + tap];
        } else if (i < ncw + nrs) {
            i -= ncw;
            int j = i & 7, lane = (i >> 3) & 63, rest = i >> 9;
            int ks = rest & 3; rest >>= 2;
            int mt = rest & 7; int l = rest >> 3;
            int m = mt * 16 + (lane & 15);
            int k = ks * 32 + (lane >> 4) * 8 + j;
            rsw[i] = (_Float16)res_w[((size_t)l * 128 + m) * 128 + k];
        } else if (i < ncw + nrs + nsk) {
            i -= ncw + nrs;
            int j = i & 7, lane = (i >> 3) & 63, rest = i >> 9;
            int ks = rest & 3; rest >>= 2;
            int mt = rest & 15; int l = rest >> 4;
            int m = mt * 16 + (lane & 15);
            int k = ks * 32 + (lane >> 4) * 8 + j;
            skw[i] = (_Float16)skip_w[((size_t)l * 256 + m) * 128 + k];
        } else if (i < ncw + nrs + nsk + nab) {
            i -= ncw + nrs + nsk;
            int j = i & 7, lane = (i >> 3) & 63, rest = i >> 9;
            int ks = rest & 7; int mt = rest >> 3;
            aw[i] = (_Float16)a_w[(mt * 16 + (lane & 15)) * 256 + ks * 32 + (lane >> 4) * 8 + j];
        } else if (i < ncw + nrs + nsk + 2 * nab) {
            i -= ncw + nrs + nsk + nab;
            int j = i & 7, lane = (i >> 3) & 63, rest = i >> 9;
            int ks = rest & 7; int mt = rest >> 3;
            bw[i] = (_Float16)b_w[(mt * 16 + (lane & 15)) * 256 + ks * 32 + (lane >> 4) * 8 + j];
        } else if (i < ncw + nrs + nsk + 2 * nab + ncb) {
            i -= ncw + nrs + nsk + 2 * nab;
            int mp = i & 255; int l = i >> 8;
            cbp[i] = conv_b[l * 256 + (mp >> 1) + (mp & 1) * 128];
        } else {
            i -= ncw + nrs + nsk + 2 * nab + ncb;
            float s = 0.f;
            for (int l = 0; l < NLAYERS; ++l) s += skip_b[l * 256 + i];
            ssum[i] = s;
        }
    }
}

// ---------------- front: h0 (f16, [n][t][c]) ----------------
__global__ void front_kernel(const float* __restrict__ x,
                             const float* __restrict__ w_shift,
                             const float* __restrict__ b_shift,
                             _Float16* __restrict__ h) {
    const int n = blockIdx.y;
    const int t = blockIdx.x * 256 + threadIdx.x;
    float x1 = (t >= 1) ? x[n * WLEN + t - 1] : 0.0f;
    float x2 = (t >= 2) ? x[n * WLEN + t - 2] : 0.0f;
    _Float16* hq = h + ((size_t)n * WLEN + t) * 128;
    #pragma unroll
    for (int c0 = 0; c0 < 128; c0 += 8) {
        half8 v;
        #pragma unroll
        for (int j = 0; j < 8; ++j) {
            int c = c0 + j;
            v[j] = (_Float16)fmaf(w_shift[2 * c], x2,
                                  fmaf(w_shift[2 * c + 1], x1, b_shift[c]));
        }
        *(half8*)&hq[c0] = v;
    }
}

// ---------------- fused stack kernel: 6 layers d=1..32 in LDS ----------------
template <bool FIRST>
__global__ __launch_bounds__(512, 4) void stack_kernel(
    const _Float16* __restrict__ h_in, _Float16* __restrict__ h_out,
    _Float16* __restrict__ chunk,
    const _Float16* __restrict__ cw0, const float* __restrict__ cb0,
    const _Float16* __restrict__ rsw0, const float* __restrict__ rb0,
    const _Float16* __restrict__ skw0, const float* __restrict__ ssum) {
    __shared__ _Float16 SMEM[2 * HW * GROW];  // 69632 B -> 2 blocks/CU
    _Float16* H = SMEM;              // h window, updated in place per layer
    _Float16* G = SMEM + HW * GROW;  // gated
    const int n = blockIdx.y, tb = blockIdx.x, t0 = tb * TT;
    const int tid = threadIdx.x;
    const int wave = __builtin_amdgcn_readfirstlane(tid >> 6);  // 0..7
    const int lane = tid & 63, q = lane >> 4, ml = lane & 15;

    // ---- skip accumulator (persistent f32 across the 6 layers)
    floatx4 sacc[2][4];
    if (FIRST) {
        #pragma unroll
        for (int mt = 0; mt < 2; ++mt)
            #pragma unroll
            for (int r = 0; r < 4; ++r) {
                float bias = ssum[32 * wave + mt * 16 + q * 4 + r];
                #pragma unroll
                for (int nt = 0; nt < 4; ++nt) sacc[mt][nt][r] = bias;
            }
    } else {
        const _Float16* cp = chunk + ((size_t)n * NTB + tb) * 16384;
        #pragma unroll
        for (int mt = 0; mt < 2; ++mt)
            #pragma unroll
            for (int nt = 0; nt < 4; ++nt) {
                size_t o = (size_t)((((wave * 2 + mt) * 4) + nt) * 64 + lane) * 4;
                half4 v = *(const half4*)&cp[o];
                #pragma unroll
                for (int r = 0; r < 4; ++r) sacc[mt][nt][r] = (float)v[r];
            }
    }

    // ---- stage 128-row window (t0-64 .. t0+63); t<0 rows = 0 (causal pad)
    const _Float16* hn = h_in + (size_t)n * WLEN * 128;
    #pragma unroll
    for (int it = 0; it < 4; ++it) {
        int idx = it * 512 + tid;        // 0..2047
        int seg = idx & 15;              // 16B segment (8 f16)
        int w = idx >> 4;                // 0..127
        int src_t = t0 - 64 + w;
        half8 v = (half8)(_Float16)0.0f;
        if (src_t >= 0)
            v = *(const half8*)&hn[(size_t)src_t * 128 + seg * 8];
        *(half8*)&H[w * GROW + seg * 8] = v;
    }
    __syncthreads();

    const _Float16* cw  = cw0;
    const float*    cb  = cb0;
    const _Float16* rsw = rsw0;
    const float*    rb  = rb0;
    const _Float16* skw = skw0;

    #pragma clang loop unroll(disable)
    for (int j = 0; j < 6; ++j) {
        const int d = 1 << j;

        // ---- conv GEMM + GLU, two 64-row passes over the window
        #pragma unroll
        for (int np = 0; np < 2; ++np) {
            floatx4 acc[2][4];
            #pragma unroll
            for (int mt = 0; mt < 2; ++mt)
                #pragma unroll
                for (int r = 0; r < 4; ++r) {
                    float bias = cb[32 * wave + mt * 16 + q * 4 + r];
                    #pragma unroll
                    for (int nt = 0; nt < 4; ++nt) acc[mt][nt][r] = bias;
                }
            #pragma unroll
            for (int hp = 0; hp < 2; ++hp) {
                for (int ks = 0; ks < 4; ++ks) {
                    half8 a[2];
                    #pragma unroll
                    for (int mt = 0; mt < 2; ++mt)
                        a[mt] = *(const half8*)&cw[((((2 * wave + mt) * 8) + hp * 4 + ks) * 64 + lane) * 8];
                    #pragma unroll
                    for (int nt = 0; nt < 4; ++nt) {
                        int row = np * 64 + nt * 16 + ml;
                        if (!hp) { row -= d; if (row < 0) row = 0; }  // tap0 = t-d, clamped
                        half8 b = *(const half8*)&H[row * GROW + ks * 32 + q * 8];
                        #pragma unroll
                        for (int mt = 0; mt < 2; ++mt)
                            acc[mt][nt] = __builtin_amdgcn_mfma_f32_16x16x32_f16(a[mt], b, acc[mt][nt], 0, 0, 0);
                    }
                }
            }
            // GLU -> G (separate buffer from H: no barrier needed before write)
            #pragma unroll
            for (int mt = 0; mt < 2; ++mt)
                #pragma unroll
                for (int nt = 0; nt < 4; ++nt) {
                    float g0 = acc[mt][nt][0] * sigmoidf_(acc[mt][nt][1]);
                    float g1 = acc[mt][nt][2] * sigmoidf_(acc[mt][nt][3]);
                    _Float16 p[2] = {(_Float16)g0, (_Float16)g1};
                    *(uint32_t*)&G[(np * 64 + nt * 16 + ml) * GROW + 16 * wave + mt * 8 + 2 * q] = *(uint32_t*)p;
                }
        }
        __syncthreads();  // G complete before skip/res read it

        // ---- skip GEMM over the valid tile (window rows 64..127) -> sacc
        #pragma unroll
        for (int ks = 0; ks < 4; ++ks) {
            half8 a[2];
            #pragma unroll
            for (int mt = 0; mt < 2; ++mt)
                a[mt] = *(const half8*)&skw[((((2 * wave + mt) * 4) + ks) * 64 + lane) * 8];
            #pragma unroll
            for (int nt = 0; nt < 4; ++nt) {
                half8 b = *(const half8*)&G[(64 + nt * 16 + ml) * GROW + ks * 32 + q * 8];
                #pragma unroll
                for (int mt = 0; mt < 2; ++mt)
                    sacc[mt][nt] = __builtin_amdgcn_mfma_f32_16x16x32_f16(a[mt], b, sacc[mt][nt], 0, 0, 0);
            }
        }

        // ---- res GEMM + in-place H update (each (w,c) cell RMW'd by its owner)
        #pragma unroll
        for (int np = 0; np < 2; ++np) {
            floatx4 racc[4];
            #pragma unroll
            for (int r = 0; r < 4; ++r) {
                float bias = rb[16 * wave + q * 4 + r];
                #pragma unroll
                for (int nt = 0; nt < 4; ++nt) racc[nt][r] = bias;
            }
            #pragma unroll
            for (int ks = 0; ks < 4; ++ks) {
                half8 a = *(const half8*)&rsw[(((wave * 4) + ks) * 64 + lane) * 8];
                #pragma unroll
                for (int nt = 0; nt < 4; ++nt) {
                    half8 b = *(const half8*)&G[(np * 64 + nt * 16 + ml) * GROW + ks * 32 + q * 8];
                    racc[nt] = __builtin_amdgcn_mfma_f32_16x16x32_f16(a, b, racc[nt], 0, 0, 0);
                }
            }
            #pragma unroll
            for (int nt = 0; nt < 4; ++nt) {
                int w = np * 64 + nt * 16 + ml;
                int c = 16 * wave + q * 4;
                half4 hv = *(const half4*)&H[w * GROW + c];
                half4 o;
                #pragma unroll
                for (int r = 0; r < 4; ++r)
                    o[r] = (_Float16)(racc[nt][r] + (float)hv[r]);
                *(half4*)&H[w * GROW + c] = o;
            }
        }
        __syncthreads();  // H updated before next layer's conv reads

        cw  += 65536; cb += 256; rsw += 16384; rb += 128; skw += 32768;
    }

    // ---- store h_out: window rows 64..127 -> t0..t0+63
    _Float16* ho = h_out + (size_t)n * WLEN * 128;
    #pragma unroll
    for (int it = 0; it < 2; ++it) {
        int idx = it * 512 + tid;        // 0..1023
        int seg = idx & 15;
        int w64 = idx >> 4;              // 0..63
        *(half8*)&ho[(size_t)(t0 + w64) * 128 + seg * 8] =
            *(const half8*)&H[(64 + w64) * GROW + seg * 8];
    }

    // ---- store skip accumulator (f16 frag-linear, same layout as singles/head)
    {
        _Float16* cp = chunk + ((size_t)n * NTB + tb) * 16384;
        #pragma unroll
        for (int mt = 0; mt < 2; ++mt)
            #pragma unroll
            for (int nt = 0; nt < 4; ++nt) {
                size_t o = (size_t)((((wave * 2 + mt) * 4) + nt) * 64 + lane) * 4;
                half4 v;
                #pragma unroll
                for (int r = 0; r < 4; ++r) v[r] = (_Float16)sacc[mt][nt][r];
                *(half4*)&cp[o] = v;
            }
    }
}

// ---------------- single residual layer (d>=64), 8 waves (round-7) ----------------
__global__ __launch_bounds__(512, 8) void layer_kernel(
    const _Float16* __restrict__ h_in, _Float16* __restrict__ h_out,
    _Float16* __restrict__ chunk,
    const _Float16* __restrict__ cw, const float* __restrict__ cb,
    const _Float16* __restrict__ rsw, const float* __restrict__ rb,
    const _Float16* __restrict__ skw, int d) {
    __shared__ _Float16 SMEM[2 * TT * GROW];  // 34816 B -> 4 blocks/CU
    _Float16* X0 = SMEM;
    _Float16* X1 = SMEM + TT * GROW;
    _Float16* G  = X0;  // alias: tap0 dead after conv reads
    const int n = blockIdx.y, tb = blockIdx.x, t0 = tb * TT;
    const int tid = threadIdx.x;
    const int wave = __builtin_amdgcn_readfirstlane(tid >> 6);  // 0..7
    const int lane = tid & 63, q = lane >> 4, ml = lane & 15;

    const _Float16* hn = h_in + (size_t)n * WLEN * 128;
    #pragma unroll
    for (int it = 0; it < 4; ++it) {
        int idx = it * 512 + tid;
        int seg = idx & 15;
        int rowc = (idx >> 4) & 63;
        int tap = idx >> 10;
        int src_t = t0 + rowc - (tap ? 0 : d);
        half8 v = (half8)(_Float16)0.0f;
        if (src_t >= 0)
            v = *(const half8*)&hn[(size_t)src_t * 128 + seg * 8];
        _Float16* Xb = tap ? X1 : X0;
        *(half8*)&Xb[rowc * GROW + seg * 8] = v;
    }
    __syncthreads();

    floatx4 acc[2][4];
    #pragma unroll
    for (int mt = 0; mt < 2; ++mt)
        #pragma unroll
        for (int r = 0; r < 4; ++r) {
            float bias = cb[32 * wave + mt * 16 + q * 4 + r];
            #pragma unroll
            for (int nt = 0; nt < 4; ++nt) acc[mt][nt][r] = bias;
        }
    #pragma unroll
    for (int hp = 0; hp < 2; ++hp) {
        const _Float16* Xb = hp ? X1 : X0;
        for (int ks = 0; ks < 4; ++ks) {
            half8 a[2];
            #pragma unroll
            for (int mt = 0; mt < 2; ++mt)
                a[mt] = *(const half8*)&cw[((((2 * wave + mt) * 8) + hp * 4 + ks) * 64 + lane) * 8];
            #pragma unroll
            for (int nt = 0; nt < 4; ++nt) {
                half8 b = *(const half8*)&Xb[(nt * 16 + ml) * GROW + ks * 32 + q * 8];
                #pragma unroll
                for (int mt = 0; mt < 2; ++mt)
                    acc[mt][nt] = __builtin_amdgcn_mfma_f32_16x16x32_f16(a[mt], b, acc[mt][nt], 0, 0, 0);
            }
        }
    }
    __syncthreads();

    #pragma unroll
    for (int mt = 0; mt < 2; ++mt)
        #pragma unroll
        for (int nt = 0; nt < 4; ++nt) {
            float g0 = acc[mt][nt][0] * sigmoidf_(acc[mt][nt][1]);
            float g1 = acc[mt][nt][2] * sigmoidf_(acc[mt][nt][3]);
            _Float16 p[2] = {(_Float16)g0, (_Float16)g1};
            *(uint32_t*)&G[(nt * 16 + ml) * GROW + 16 * wave + mt * 8 + 2 * q] = *(uint32_t*)p;
        }
    __syncthreads();

    {
        floatx4 sacc[2][4];
        #pragma unroll
        for (int mt = 0; mt < 2; ++mt)
            #pragma unroll
            for (int nt = 0; nt < 4; ++nt)
                #pragma unroll
                for (int r = 0; r < 4; ++r) sacc[mt][nt][r] = 0.0f;
        #pragma unroll
        for (int ks = 0; ks < 4; ++ks) {
            half8 a[2];
            #pragma unroll
            for (int mt = 0; mt < 2; ++mt)
                a[mt] = *(const half8*)&skw[((((2 * wave + mt) * 4) + ks) * 64 + lane) * 8];
            #pragma unroll
            for (int nt = 0; nt < 4; ++nt) {
                half8 b = *(const half8*)&G[(nt * 16 + ml) * GROW + ks * 32 + q * 8];
                #pragma unroll
                for (int mt = 0; mt < 2; ++mt)
                    sacc[mt][nt] = __builtin_amdgcn_mfma_f32_16x16x32_f16(a[mt], b, sacc[mt][nt], 0, 0, 0);
            }
        }
        _Float16* cp = chunk + ((size_t)n * NTB + tb) * 16384;
        #pragma unroll
        for (int mt = 0; mt < 2; ++mt)
            #pragma unroll
            for (int nt = 0; nt < 4; ++nt) {
                size_t o = (size_t)((((wave * 2 + mt) * 4) + nt) * 64 + lane) * 4;
                half4 v = *(const half4*)&cp[o];
                half4 w;
                #pragma unroll
                for (int r = 0; r < 4; ++r)
                    w[r] = (_Float16)(sacc[mt][nt][r] + (float)v[r]);
                *(half4*)&cp[o] = w;
            }
    }

    {
        floatx4 racc[4];
        #pragma unroll
        for (int r = 0; r < 4; ++r) {
            float bias = rb[16 * wave + q * 4 + r];
            #pragma unroll
            for (int nt = 0; nt < 4; ++nt) racc[nt][r] = bias;
        }
        #pragma unroll
        for (int ks = 0; ks < 4; ++ks) {
            half8 a = *(const half8*)&rsw[(((wave * 4) + ks) * 64 + lane) * 8];
            #pragma unroll
            for (int nt = 0; nt < 4; ++nt) {
                half8 b = *(const half8*)&G[(nt * 16 + ml) * GROW + ks * 32 + q * 8];
                racc[nt] = __builtin_amdgcn_mfma_f32_16x16x32_f16(a, b, racc[nt], 0, 0, 0);
            }
        }
        _Float16* ho = h_out + (size_t)n * WLEN * 128;
        #pragma unroll
        for (int nt = 0; nt < 4; ++nt) {
            int tt = nt * 16 + ml;
            int c = 16 * wave + q * 4;
            half4 hv = *(const half4*)&X1[tt * GROW + c];
            half4 o;
            #pragma unroll
            for (int r = 0; r < 4; ++r)
                o[r] = (_Float16)(racc[nt][r] + (float)hv[r]);
            *(half4*)&ho[(size_t)(t0 + tt) * 128 + c] = o;
        }
    }
}

// ---------------- head (round-7, 8 waves) ----------------
__global__ __launch_bounds__(512, 8) void head_kernel(
    float* __restrict__ out, const _Float16* __restrict__ chunk,
    const _Float16* __restrict__ aw, const float* __restrict__ ab,
    const _Float16* __restrict__ bw, const float* __restrict__ bb) {
    __shared__ _Float16 X[TT * XROW];
    const int n = blockIdx.y, tb = blockIdx.x, t0 = tb * TT;
    const int tid = threadIdx.x;
    const int wave = __builtin_amdgcn_readfirstlane(tid >> 6);
    const int lane = tid & 63, q = lane >> 4, ml = lane & 15;

    {
        const _Float16* cp = chunk + ((size_t)n * NTB + tb) * 16384;
        #pragma unroll
        for (int mt = 0; mt < 2; ++mt)
            #pragma unroll
            for (int nt = 0; nt < 4; ++nt) {
                size_t o = (size_t)((((wave * 2 + mt) * 4) + nt) * 64 + lane) * 4;
                half4 v = *(const half4*)&cp[o];
                half4 z;
                #pragma unroll
                for (int r = 0; r < 4; ++r)
                    z[r] = (_Float16)fmaxf((float)v[r], 0.0f);
                *(half4*)&X[(nt * 16 + ml) * XROW + 32 * wave + mt * 16 + q * 4] = z;
            }
    }
    __syncthreads();

    floatx4 acc[2][4];
    #pragma unroll
    for (int mt = 0; mt < 2; ++mt)
        #pragma unroll
        for (int r = 0; r < 4; ++r) {
            float bias = ab[32 * wave + mt * 16 + q * 4 + r];
            #pragma unroll
            for (int nt = 0; nt < 4; ++nt) acc[mt][nt][r] = bias;
        }
    for (int ks = 0; ks < 8; ++ks) {
        half8 a[2];
        #pragma unroll
        for (int mt = 0; mt < 2; ++mt)
            a[mt] = *(const half8*)&aw[((((2 * wave + mt) * 8) + ks) * 64 + lane) * 8];
        #pragma unroll
        for (int nt = 0; nt < 4; ++nt) {
            half8 b = *(const half8*)&X[(nt * 16 + ml) * XROW + ks * 32 + q * 8];
            #pragma unroll
            for (int mt = 0; mt < 2; ++mt)
                acc[mt][nt] = __builtin_amdgcn_mfma_f32_16x16x32_f16(a[mt], b, acc[mt][nt], 0, 0, 0);
        }
    }
    __syncthreads();
    #pragma unroll
    for (int mt = 0; mt < 2; ++mt)
        #pragma unroll
        for (int nt = 0; nt < 4; ++nt) {
            half4 z;
            #pragma unroll
            for (int r = 0; r < 4; ++r)
                z[r] = (_Float16)fmaxf(acc[mt][nt][r], 0.0f);
            *(half4*)&X[(nt * 16 + ml) * XROW + 32 * wave + mt * 16 + q * 4] = z;
        }
    __syncthreads();

    #pragma unroll
    for (int mt = 0; mt < 2; ++mt)
        #pragma unroll
        for (int r = 0; r < 4; ++r) {
            float bias = bb[32 * wave + mt * 16 + q * 4 + r];
            #pragma unroll
            for (int nt = 0; nt < 4; ++nt) acc[mt][nt][r] = bias;
        }
    for (int ks = 0; ks < 8; ++ks) {
        half8 a[2];
        #pragma unroll
        for (int mt = 0; mt < 2; ++mt)
            a[mt] = *(const half8*)&bw[((((2 * wave + mt) * 8) + ks) * 64 + lane) * 8];
        #pragma unroll
        for (int nt = 0; nt < 4; ++nt) {
            half8 b = *(const half8*)&X[(nt * 16 + ml) * XROW + ks * 32 + q * 8];
            #pragma unroll
            for (int mt = 0; mt < 2; ++mt)
                acc[mt][nt] = __builtin_amdgcn_mfma_f32_16x16x32_f16(a[mt], b, acc[mt][nt], 0, 0, 0);
        }
    }
    float* on = out + (size_t)n * S * WLEN;
    #pragma unroll
    for (int mt = 0; mt < 2; ++mt)
        #pragma unroll
        for (int nt = 0; nt < 4; ++nt)
            #pragma unroll
            for (int r = 0; r < 4; ++r) {
                int o = 32 * wave + mt * 16 + q * 4 + r;
                int tt = t0 + nt * 16 + ml;
                on[(size_t)o * WLEN + tt] = acc[mt][nt][r];
            }
}

extern "C" void kernel_launch(void* const* d_in, const int* in_sizes, int n_in,
                              void* d_out, int out_size, void* d_ws, size_t ws_size,
                              hipStream_t stream) {
    (void)in_sizes; (void)n_in; (void)out_size; (void)ws_size;
    const float* x       = (const float*)d_in[0];
    const float* w_shift = (const float*)d_in[1];
    const float* b_shift = (const float*)d_in[2];
    const float* conv_w  = (const float*)d_in[3];
    const float* conv_b  = (const float*)d_in[4];
    const float* res_w   = (const float*)d_in[5];
    const float* res_b   = (const float*)d_in[6];
    const float* skip_w  = (const float*)d_in[7];
    const float* skip_b  = (const float*)d_in[8];
    const float* a_w     = (const float*)d_in[9];
    const float* a_b     = (const float*)d_in[10];
    const float* b_w     = (const float*)d_in[11];
    const float* b_b     = (const float*)d_in[12];
    float* out = (float*)d_out;

    char* ws = (char*)d_ws;
    size_t off = 0;
    _Float16* hA    = (_Float16*)(ws + off); off += (size_t)NB * WLEN * 128 * 2;
    _Float16* hB    = (_Float16*)(ws + off); off += (size_t)NB * WLEN * 128 * 2;
    _Float16* chunk = (_Float16*)(ws + off); off += (size_t)NB * NTB * 16384 * 2;
    _Float16* cw  = (_Float16*)(ws + off); off += (size_t)NLAYERS * 256 * 256 * 2;
    _Float16* rsw = (_Float16*)(ws + off); off += (size_t)NLAYERS * 128 * 128 * 2;
    _Float16* skw = (_Float16*)(ws + off); off += (size_t)NLAYERS * 256 * 128 * 2;
    _Float16* aw  = (_Float16*)(ws + off); off += 256 * 256 * 2;
    _Float16* bw  = (_Float16*)(ws + off); off += 256 * 256 * 2;
    float* cbp  = (float*)(ws + off); off += (size_t)NLAYERS * 256 * 4;
    float* ssum = (float*)(ws + off); off += 256 * 4;
    // total ~74.3 MB

    prep_kernel<<<512, 256, 0, stream>>>(conv_w, res_w, skip_w, a_w, b_w,
                                         conv_b, skip_b,
                                         cw, rsw, skw, aw, bw, cbp, ssum);
    front_kernel<<<dim3(WLEN / 256, NB), 256, 0, stream>>>(x, w_shift, b_shift, hA);

    const dim3 grid(NTB, NB);
    _Float16* hin = hA;
    _Float16* hout = hB;
    for (int s = 0; s < 3; ++s) {
        const int l0 = s * 10;
        // fused layers l0 .. l0+5 (d = 1..32)
        if (s == 0)
            stack_kernel<true><<<grid, 512, 0, stream>>>(
                hin, hout, chunk,
                cw + (size_t)l0 * 65536, cbp + l0 * 256,
                rsw + (size_t)l0 * 16384, res_b + l0 * 128,
                skw + (size_t)l0 * 32768, ssum);
        else
            stack_kernel<false><<<grid, 512, 0, stream>>>(
                hin, hout, chunk,
                cw + (size_t)l0 * 65536, cbp + l0 * 256,
                rsw + (size_t)l0 * 16384, res_b + l0 * 128,
                skw + (size_t)l0 * 32768, ssum);
        { _Float16* tmp = hin; hin = hout; hout = tmp; }
        // single layers l0+6 .. l0+9 (d = 64..512)
        for (int jj = 6; jj < 10; ++jj) {
            const int l = l0 + jj;
            const int dil = 1 << jj;
            layer_kernel<<<grid, 512, 0, stream>>>(
                hin, hout, chunk,
                cw + (size_t)l * 65536, cbp + l * 256,
                rsw + (size_t)l * 16384, res_b + l * 128,
                skw + (size_t)l * 32768, dil);
            _Float16* tmp = hin; hin = hout; hout = tmp;
        }
    }

    head_kernel<<<grid, 512, 0, stream>>>(out, chunk, aw, a_b, bw, b_b);
}